// Round 9
// baseline (396.111 us; speedup 1.0000x reference)
//
#include <hip/hip_runtime.h>
#include <hip/hip_bf16.h>
#include <math.h>

// Problem: Attention_58102317580396
// B=2, S=2048, D=2048, H=16, DH=128. Inputs/outputs FP32; internal bf16 MFMA.
// Pipeline: cvt3(x,w_in,w_out)->bf16 (fused) ; GEMM1 x@w_in^T -> P[4096][6144];
//           flash attn -> O[4096][2048] ; GEMM2 O@w_out^T -> out fp32.
// R17: consolidation + XCD locality.
//  (a) GEMM1 re-merged to one 1536-block dispatch (observability split no
//      longer needed; attn fully characterized: 94-97us, barrier-bound, VALU
//      trims neutral — R16 falsified the VALU theory, attn frozen).
//  (b) gemm_bt: bijective XCD-chunked block swizzle (T1). Default round-robin
//      puts consecutive blockIdx.x (same A-panel) on 8 different XCDs ->
//      measured FETCH 95MB vs 33MB ideal (3x A over-fetch). Swizzle gives
//      each XCD a contiguous run of rows; predict FETCH -> 40-55MB.
//      Applies to GEMM1 (1536%8==0) and GEMM2 (512%8==0).
// attn (R16 exp2 form), cvt3 unchanged.
// Verified layouts (learn_hip m89/m120):
//   A-frag: m=lane&15, k=quad*8+j ; B-frag: n=lane&15, k=quad*8+j (same addr)
//   C/D:    col=lane&15, row=quad*4+reg

typedef short bf16x8 __attribute__((ext_vector_type(8)));
typedef float f32x4 __attribute__((ext_vector_type(4)));

#define NEG_BIG -30000.0f

__device__ __forceinline__ short f2bf(float f) {
    union { float f; unsigned u; } v; v.f = f;
    unsigned r = v.u + 0x7fffu + ((v.u >> 16) & 1u);  // RNE
    return (short)(r >> 16);
}

__device__ __forceinline__ int pack2bf(float a, float b) {
    return (int)((((unsigned)f2bf(b)) << 16) | (((unsigned)f2bf(a)) & 0xffffu));
}

#define GLDS16(g, l) \
    __builtin_amdgcn_global_load_lds((const __attribute__((address_space(1))) void*)(g), \
                                     (__attribute__((address_space(3))) void*)(l), 16, 0, 0)

// Fused fp32 -> bf16 for the three inputs (all sizes divisible by 1024).
// c1 = nx/4, c2 = c1 + nwi/4 (thread-granule boundaries).
__global__ __launch_bounds__(256) void cvt3_f32_bf16(const float* __restrict__ x,  short* __restrict__ dx,
                                                     const float* __restrict__ wi, short* __restrict__ dwi,
                                                     const float* __restrict__ wo, short* __restrict__ dwo,
                                                     int c1, int c2) {
    const int g = blockIdx.x * blockDim.x + threadIdx.x;
    const float* s; short* d; int off;
    if (g < c1)      { s = x;  d = dx;  off = g; }
    else if (g < c2) { s = wi; d = dwi; off = g - c1; }
    else             { s = wo; d = dwo; off = g - c2; }
    float4 v = *(const float4*)(s + (size_t)off * 4);
    short4 o;
    o.x = f2bf(v.x); o.y = f2bf(v.y); o.z = f2bf(v.z); o.w = f2bf(v.w);
    *(short4*)(d + (size_t)off * 4) = o;
}

// C[M][N] = A[M][K] * B[N][K]^T  (bf16 in, fp32 acc, bf16 or fp32 out)
// block 256 = 4 waves; block tile 128xBN; wave tile 64x(BN/2); BK=64 as two
// 32-k sub-tiles per barrier pair. LDS layout per sub: chunk-ordered rows x32.
// XCD-chunked bijective block swizzle (requires grid total % 8 == 0): each
// XCD gets a contiguous run of flat block ids -> A-panels (shared along
// grid.x) are fetched by 1 XCD instead of 8.
template <int BN, bool F32OUT>
__global__ __launch_bounds__(256) void gemm_bt(const short* __restrict__ A,
                                               const short* __restrict__ Bm,
                                               void* __restrict__ Cv,
                                               int N, int K) {
    constexpr int NT = BN / 32;               // n-acc tiles per wave
    constexpr int SUBA = 128 * 32;            // shorts per A sub-tile
    constexpr int SUBB = BN * 32;             // shorts per B sub-tile
    __shared__ short sA[2 * SUBA];
    __shared__ short sB[2 * SUBB];
    const int lane = threadIdx.x & 63;
    const int w = threadIdx.x >> 6;
    const int l15 = lane & 15, quad = lane >> 4;

    // XCD swizzle: flat id -> chunked id (bijective when total%8==0)
    const int total = (int)(gridDim.x * gridDim.y);
    const int flat = (int)(blockIdx.y * gridDim.x + blockIdx.x);
    const int cpx = total >> 3;
    const int swz = (flat & 7) * cpx + (flat >> 3);
    const int bx = swz % (int)gridDim.x;
    const int by = swz / (int)gridDim.x;
    const int bm0 = by * 128, bn0 = bx * BN;

    const int c1 = w * 64 + lane;             // chunk id 0..255
    const short* gA = A + (size_t)(bm0 + (c1 >> 2)) * K + (c1 & 3) * 8;
    const short* gB = Bm + (size_t)(bn0 + (c1 >> 2)) * K + (c1 & 3) * 8;
    const size_t half64 = (size_t)64 * K;     // chunk +256 -> row +64
    short* lA1 = sA + w * 512;                // wave-uniform GLDS bases
    short* lA2 = sA + 2048 + w * 512;
    short* lB1 = sB + w * 512;
    short* lB2 = sB + 2048 + w * 512;         // only when BN==128

    const int wm = (w >> 1) * 64, wn = (w & 1) * (BN / 2);
    const short* pa = sA + (wm + l15) * 32 + quad * 8;
    const short* pb = sB + (wn + l15) * 32 + quad * 8;

    f32x4 acc[4][NT] = {};
    for (int k0 = 0; k0 < K; k0 += 64) {
        #pragma unroll
        for (int s = 0; s < 2; s++) {
            const int ks = k0 + s * 32;
            GLDS16(gA + ks, lA1 + s * SUBA);
            GLDS16(gA + half64 + ks, lA2 + s * SUBA);
            GLDS16(gB + ks, lB1 + s * SUBB);
            if constexpr (BN == 128) GLDS16(gB + half64 + ks, lB2 + s * SUBB);
        }
        __syncthreads();
        #pragma unroll
        for (int s = 0; s < 2; s++) {
            bf16x8 af[4], bf[NT];
            #pragma unroll
            for (int mt = 0; mt < 4; mt++) af[mt] = *(const bf16x8*)(pa + s * SUBA + mt * 512);
            #pragma unroll
            for (int nt = 0; nt < NT; nt++) bf[nt] = *(const bf16x8*)(pb + s * SUBB + nt * 512);
            #pragma unroll
            for (int mt = 0; mt < 4; mt++)
                #pragma unroll
                for (int nt = 0; nt < NT; nt++)
                    acc[mt][nt] = __builtin_amdgcn_mfma_f32_16x16x32_bf16(af[mt], bf[nt], acc[mt][nt], 0, 0, 0);
        }
        __syncthreads();
    }
    #pragma unroll
    for (int mt = 0; mt < 4; mt++)
        #pragma unroll
        for (int nt = 0; nt < NT; nt++)
            #pragma unroll
            for (int r = 0; r < 4; r++) {
                int row = bm0 + wm + mt * 16 + quad * 4 + r;
                int col = bn0 + wn + nt * 16 + l15;
                if (F32OUT)
                    ((float*)Cv)[(size_t)row * N + col] = acc[mt][nt][r];
                else
                    ((short*)Cv)[(size_t)row * N + col] = f2bf(acc[mt][nt][r]);
            }
}

// ---------------------------------------------------------------------------
// Flash attention, causal, S^T formulation. q-tile 128 rows, 8 waves (512 thr).
// grid = 512 blocks; qt = b ? 15-t0 : t0 so co-resident pairs (ids +256) do
// constant work. KV tile = 64 keys/iter. Waves 0-3 stage K (4x GLDS,
// XOR-swizzled), waves 4-7 stage V (transposed, pitch 72). Per-wave compute:
// 16 q-rows; waves skip tiles fully above their causal diagonal.
// Scores in RAW units; exp via exp2 with c2 = scale*log2e folded into a fma.
// (Measured R13/R15/R16: 94-97us, MfmaUtil ~14.5, VALU ~34, conflicts 6.49e6
//  — barrier/latency-bound; VALU trims neutral; FROZEN.)
#define VP2 72
__global__ __launch_bounds__(512) void attn_kernel(const short* __restrict__ P,
                                                   short* __restrict__ O) {
    constexpr int S = 2048, ROWW = 6144, HD = 2048;
    const int id = blockIdx.x;
    const int b = id >> 8;
    const int rr = id & 255;
    const int h = rr & 15;
    const int t0 = rr >> 4;                    // 0..15
    const int qt = b ? (15 - t0) : t0;         // work balance across pairs
    const int wave = threadIdx.x >> 6, lane = threadIdx.x & 63;
    const int l15 = lane & 15, quad = lane >> 4;
    const int qRow = qt * 128 + wave * 16;
    const short* Pb = P + (size_t)b * S * ROWW;
    const short* Qp = Pb + h * 384;
    const short* Kp = Qp + 128;
    const short* Vp = Qp + 256;

    __shared__ short sK[2][64 * 128];   // swizzled chunk layout, 16 KB each
    __shared__ short sVt[2][128 * VP2]; // [d][key], 18 KB each

    // Q fragments (B operand, n=q=l15, k=d=quad*8+j)
    bf16x8 qf[4];
    #pragma unroll
    for (int f = 0; f < 4; f++)
        qf[f] = *(const bf16x8*)(Qp + (size_t)(qRow + l15) * ROWW + f * 32 + quad * 8);

    const bool isK = wave < 4;
    const int c1 = (wave & 3) * 64 + lane;
    const int krow1 = c1 >> 4;                 // 0..15
    const int kcol = ((c1 & 15) ^ (krow1 & 15)) * 8;
    const short* gK1 = Kp + (size_t)krow1 * ROWW + kcol;
    const short* gK2 = Kp + (size_t)(krow1 + 16) * ROWW + kcol;
    const short* gK3 = Kp + (size_t)(krow1 + 32) * ROWW + kcol;
    const short* gK4 = Kp + (size_t)(krow1 + 48) * ROWW + kcol;
    const int ldsOff1 = (wave & 3) * 512;
    const int ldsOff2 = 2048 + ldsOff1;
    const int ldsOff3 = 4096 + ldsOff1;
    const int ldsOff4 = 6144 + ldsOff1;
    const int vt = (int)threadIdx.x - 256;
    const int vKey = vt & 31;
    const int vD0 = (vt >> 5) * 8;
    const short* gV = Vp + (size_t)vKey * ROWW + vD0;
    const short* gV2 = Vp + (size_t)(vKey + 32) * ROWW + vD0;

    const int kTiles = qt * 2 + 2;             // 64-key tiles
    const float c2 = 0.12752741594977435f;     // (1/sqrt(128))*log2(e)
    const float THRR = 90.50966799f;           // 8*sqrt(128): defer-max, raw
    const int qG = qRow + l15;

    f32x4 accO[8] = {};                        // O^T: row=d(quad*4+r), col=q(l15)
    float m_i = NEG_BIG, l_i = 0.f;

    if (isK) {
        GLDS16(gK1, &sK[0][ldsOff1]);
        GLDS16(gK2, &sK[0][ldsOff2]);
        GLDS16(gK3, &sK[0][ldsOff3]);
        GLDS16(gK4, &sK[0][ldsOff4]);
    } else {
        bf16x8 v0 = *(const bf16x8*)(gV);
        bf16x8 v1 = *(const bf16x8*)(gV + 64);
        bf16x8 v2 = *(const bf16x8*)(gV2);
        bf16x8 v3 = *(const bf16x8*)(gV2 + 64);
        #pragma unroll
        for (int j = 0; j < 8; j++) {
            sVt[0][(vD0 + j) * VP2 + vKey] = v0[j];
            sVt[0][(vD0 + 64 + j) * VP2 + vKey] = v1[j];
            sVt[0][(vD0 + j) * VP2 + vKey + 32] = v2[j];
            sVt[0][(vD0 + 64 + j) * VP2 + vKey + 32] = v3[j];
        }
    }
    __syncthreads();

    for (int kt = 0; kt < kTiles; kt++) {
        const int cur = kt & 1, nxt = cur ^ 1;
        const bool pre = (kt + 1 < kTiles);
        bf16x8 v0n, v1n, v2n, v3n;
        if (pre) {
            const size_t kOff = (size_t)(kt + 1) * 64 * ROWW;
            if (isK) {
                GLDS16(gK1 + kOff, &sK[nxt][ldsOff1]);
                GLDS16(gK2 + kOff, &sK[nxt][ldsOff2]);
                GLDS16(gK3 + kOff, &sK[nxt][ldsOff3]);
                GLDS16(gK4 + kOff, &sK[nxt][ldsOff4]);
            } else {
                v0n = *(const bf16x8*)(gV + kOff);
                v1n = *(const bf16x8*)(gV + kOff + 64);
                v2n = *(const bf16x8*)(gV2 + kOff);
                v3n = *(const bf16x8*)(gV2 + kOff + 64);
            }
        }
        if (kt * 64 <= qRow + 15) {  // wave-uniform causal diagonal skip
            // QK^T transposed: sc[hh] row=key(hh*16+quad*4+r), col=q(l15); RAW
            f32x4 sc[4] = {};
            #pragma unroll
            for (int f = 0; f < 4; f++) {       // f-outer: 4 indep MFMA chains
                const int jj = ((4 * f + quad) ^ l15) * 8;
                #pragma unroll
                for (int hh = 0; hh < 4; hh++) {
                    bf16x8 kf = *(const bf16x8*)(&sK[cur][(hh * 16 + l15) * 128 + jj]);
                    sc[hh] = __builtin_amdgcn_mfma_f32_16x16x32_bf16(kf, qf[f], sc[hh], 0, 0, 0);
                }
            }
            if (kt * 64 + 63 > qRow) {          // diagonal tiles only: mask
                #pragma unroll
                for (int hh = 0; hh < 4; hh++)
                    #pragma unroll
                    for (int r = 0; r < 4; r++) {
                        const int key = kt * 64 + hh * 16 + quad * 4 + r;
                        if (key > qG) sc[hh][r] = NEG_BIG;
                    }
            }
            float mloc = sc[0][0];
            #pragma unroll
            for (int hh = 0; hh < 4; hh++)
                #pragma unroll
                for (int r = 0; r < 4; r++) mloc = fmaxf(mloc, sc[hh][r]);
            mloc = fmaxf(mloc, __shfl_xor(mloc, 16));
            mloc = fmaxf(mloc, __shfl_xor(mloc, 32));
            if (!__all(mloc <= m_i + THRR)) {  // T13 defer-max (raw units)
                const float nm = fmaxf(m_i, mloc);
                const float alpha = __builtin_exp2f((m_i - nm) * c2);
                m_i = nm;
                l_i *= alpha;
                #pragma unroll
                for (int t = 0; t < 8; t++)
                    #pragma unroll
                    for (int r = 0; r < 4; r++) accO[t][r] *= alpha;
            }
            const float mc2 = m_i * c2;
            float ssum = 0.f;
            #pragma unroll
            for (int hh = 0; hh < 4; hh++)
                #pragma unroll
                for (int r = 0; r < 4; r++) {
                    float p = __builtin_exp2f(__builtin_fmaf(sc[hh][r], c2, -mc2));
                    sc[hh][r] = p;
                    ssum += p;
                }
            ssum += __shfl_xor(ssum, 16);
            ssum += __shfl_xor(ssum, 32);
            l_i += ssum;
            // P^T (C-layout) -> B-frag via 8 shfl per 32-key slot; PV per slot
            #pragma unroll
            for (int s = 0; s < 2; s++) {
                const int d00 = pack2bf(sc[2 * s][0], sc[2 * s][1]);
                const int d01 = pack2bf(sc[2 * s][2], sc[2 * s][3]);
                const int d10 = pack2bf(sc[2 * s + 1][0], sc[2 * s + 1][1]);
                const int d11 = pack2bf(sc[2 * s + 1][2], sc[2 * s + 1][3]);
                const int srcA = l15 + ((quad & 1) << 5);
                const int srcB = srcA + 16;
                const int s00 = __shfl(d00, srcA), s01 = __shfl(d01, srcA);
                const int s02 = __shfl(d00, srcB), s03 = __shfl(d01, srcB);
                const int s10 = __shfl(d10, srcA), s11 = __shfl(d11, srcA);
                const int s12 = __shfl(d10, srcB), s13 = __shfl(d11, srcB);
                union { int i[4]; bf16x8 v; } pu;
                const bool lo = quad < 2;
                pu.i[0] = lo ? s00 : s10;
                pu.i[1] = lo ? s01 : s11;
                pu.i[2] = lo ? s02 : s12;
                pu.i[3] = lo ? s03 : s13;
                const bf16x8 pf = pu.v;
                // PV: O^T += V^T * P^T (keys s*32..s*32+31)
                #pragma unroll
                for (int t = 0; t < 8; t++) {
                    bf16x8 vf = *(const bf16x8*)(&sVt[cur][(t * 16 + l15) * VP2 + s * 32 + quad * 8]);
                    accO[t] = __builtin_amdgcn_mfma_f32_16x16x32_bf16(vf, pf, accO[t], 0, 0, 0);
                }
            }
        }
        if (pre && !isK) {
            #pragma unroll
            for (int j = 0; j < 8; j++) {
                sVt[nxt][(vD0 + j) * VP2 + vKey] = v0n[j];
                sVt[nxt][(vD0 + 64 + j) * VP2 + vKey] = v1n[j];
                sVt[nxt][(vD0 + j) * VP2 + vKey + 32] = v2n[j];
                sVt[nxt][(vD0 + 64 + j) * VP2 + vKey + 32] = v3n[j];
            }
        }
        __syncthreads();
    }
    const float inv = 1.0f / l_i;
    #pragma unroll
    for (int t = 0; t < 8; t++) {
        short4 st;
        st.x = f2bf(accO[t][0] * inv);
        st.y = f2bf(accO[t][1] * inv);
        st.z = f2bf(accO[t][2] * inv);
        st.w = f2bf(accO[t][3] * inv);
        *(short4*)(&O[(size_t)(b * S + qG) * HD + h * 128 + t * 16 + quad * 4]) = st;
    }
}

extern "C" void kernel_launch(void* const* d_in, const int* in_sizes, int n_in,
                              void* d_out, int out_size, void* d_ws, size_t ws_size,
                              hipStream_t stream) {
    const float* x     = (const float*)d_in[0];  // [2,2048,2048] fp32
    const float* w_in  = (const float*)d_in[1];  // [6144,2048]  fp32
    const float* w_out = (const float*)d_in[2];  // [2048,2048]  fp32
    float* out = (float*)d_out;                  // [2,2048,2048] fp32

    // Workspace (96 MiB): P[4096*6144] bf16 | xO[8388608] bf16 (x_bf16 then O)
    //                     | w_in_b[6144*2048] bf16 | w_out_b[2048*2048] bf16
    short* Pbuf   = (short*)d_ws;
    short* xObuf  = Pbuf  + (size_t)4096 * 6144;
    short* winb   = xObuf + (size_t)8388608;
    short* woutb  = winb  + (size_t)6144 * 2048;

    dim3 blk(256, 1, 1);
    const int nx = 2 * 2048 * 2048, nwi = 6144 * 2048, nwo = 2048 * 2048;
    // Fused bf16 conversion of all three inputs (one launch instead of three)
    const int c1 = nx / 4, c2 = c1 + nwi / 4;
    const int totalBlocks = (nx + nwi + nwo) / 1024;
    hipLaunchKernelGGL(cvt3_f32_bf16, dim3(totalBlocks), blk, 0, stream,
                       x, xObuf, w_in, winb, w_out, woutb, c1, c2);
    // GEMM1: P = x @ w_in^T (M=4096, N=6144, K=2048), bf16 out, BN=128 BK=64,
    // single 1536-block dispatch with XCD-chunked swizzle.
    hipLaunchKernelGGL((gemm_bt<128, false>), dim3(48, 32, 1), blk, 0, stream,
                       xObuf, winb, (void*)Pbuf, 6144, 2048);
    // Flash attention (x_bf16 dead now; O overwrites it), 512 blocks x 512 thr
    hipLaunchKernelGGL(attn_kernel, dim3(512, 1, 1), dim3(512, 1, 1), 0, stream, Pbuf, xObuf);
    // GEMM2: out = O @ w_out^T (M=4096, N=2048, K=2048), fp32 out, BN=128 BK=64
    hipLaunchKernelGGL((gemm_bt<128, true>), dim3(16, 32, 1), blk, 0, stream, xObuf, woutb, (void*)out, 2048, 2048);
}

// Round 10
// 373.340 us; speedup vs baseline: 1.0610x; 1.0610x over previous
//
#include <hip/hip_runtime.h>
#include <hip/hip_bf16.h>
#include <math.h>

// Problem: Attention_58102317580396
// B=2, S=2048, D=2048, H=16, DH=128. Inputs/outputs FP32; internal bf16 MFMA.
// Pipeline: cvt3(x,w_in,w_out)->bf16 (fused) ; GEMM1 x@w_in^T -> P[4096][6144];
//           flash attn -> O[4096][2048] ; GEMM2 O@w_out^T -> out fp32.
// R18: REVERT R17's XCD swizzle (measured: FETCH 95->280MB, L2 B-thrash —
// default x-major round-robin already gives each XCD a 3MB L2-resident
// B-column set with A shared via L3; duration only +2% at 3x fetch, proving
// GEMM1 is issue/barrier-bound, not fetch-latency-bound). GEMM1 kept as ONE
// 1536-block dispatch (split was observability-only). attn (R16 exp2 form,
// frozen), cvt3, GEMM2 BN=128 unchanged.
// Measured state: GEMM1 ~125.5us (821 TF, 90% of this structure's verified
// 912 TF ceiling; both 8-phase restructures slower), attn 94-97us (barrier-
// bound; VALU trims neutral x3), GEMM2 <94us, cvt3 ~36us BW-bound.
// Verified layouts (learn_hip m89/m120):
//   A-frag: m=lane&15, k=quad*8+j ; B-frag: n=lane&15, k=quad*8+j (same addr)
//   C/D:    col=lane&15, row=quad*4+reg

typedef short bf16x8 __attribute__((ext_vector_type(8)));
typedef float f32x4 __attribute__((ext_vector_type(4)));

#define NEG_BIG -30000.0f

__device__ __forceinline__ short f2bf(float f) {
    union { float f; unsigned u; } v; v.f = f;
    unsigned r = v.u + 0x7fffu + ((v.u >> 16) & 1u);  // RNE
    return (short)(r >> 16);
}

__device__ __forceinline__ int pack2bf(float a, float b) {
    return (int)((((unsigned)f2bf(b)) << 16) | (((unsigned)f2bf(a)) & 0xffffu));
}

#define GLDS16(g, l) \
    __builtin_amdgcn_global_load_lds((const __attribute__((address_space(1))) void*)(g), \
                                     (__attribute__((address_space(3))) void*)(l), 16, 0, 0)

// Fused fp32 -> bf16 for the three inputs (all sizes divisible by 1024).
// c1 = nx/4, c2 = c1 + nwi/4 (thread-granule boundaries).
__global__ __launch_bounds__(256) void cvt3_f32_bf16(const float* __restrict__ x,  short* __restrict__ dx,
                                                     const float* __restrict__ wi, short* __restrict__ dwi,
                                                     const float* __restrict__ wo, short* __restrict__ dwo,
                                                     int c1, int c2) {
    const int g = blockIdx.x * blockDim.x + threadIdx.x;
    const float* s; short* d; int off;
    if (g < c1)      { s = x;  d = dx;  off = g; }
    else if (g < c2) { s = wi; d = dwi; off = g - c1; }
    else             { s = wo; d = dwo; off = g - c2; }
    float4 v = *(const float4*)(s + (size_t)off * 4);
    short4 o;
    o.x = f2bf(v.x); o.y = f2bf(v.y); o.z = f2bf(v.z); o.w = f2bf(v.w);
    *(short4*)(d + (size_t)off * 4) = o;
}

// C[M][N] = A[M][K] * B[N][K]^T  (bf16 in, fp32 acc, bf16 or fp32 out)
// block 256 = 4 waves; block tile 128xBN; wave tile 64x(BN/2); BK=64 as two
// 32-k sub-tiles per barrier pair. LDS layout per sub: chunk-ordered rows x32.
// NOTE: default block->XCD round-robin is kept deliberately — with x-major
// dispatch each XCD gets a fixed set of B-columns (L2-resident) and A flows
// through the shared L3. R17's row-chunked swizzle tripled HBM fetch.
template <int BN, bool F32OUT>
__global__ __launch_bounds__(256) void gemm_bt(const short* __restrict__ A,
                                               const short* __restrict__ Bm,
                                               void* __restrict__ Cv,
                                               int N, int K) {
    constexpr int NT = BN / 32;               // n-acc tiles per wave
    constexpr int SUBA = 128 * 32;            // shorts per A sub-tile
    constexpr int SUBB = BN * 32;             // shorts per B sub-tile
    __shared__ short sA[2 * SUBA];
    __shared__ short sB[2 * SUBB];
    const int lane = threadIdx.x & 63;
    const int w = threadIdx.x >> 6;
    const int l15 = lane & 15, quad = lane >> 4;
    const int bm0 = blockIdx.y * 128, bn0 = blockIdx.x * BN;

    const int c1 = w * 64 + lane;             // chunk id 0..255
    const short* gA = A + (size_t)(bm0 + (c1 >> 2)) * K + (c1 & 3) * 8;
    const short* gB = Bm + (size_t)(bn0 + (c1 >> 2)) * K + (c1 & 3) * 8;
    const size_t half64 = (size_t)64 * K;     // chunk +256 -> row +64
    short* lA1 = sA + w * 512;                // wave-uniform GLDS bases
    short* lA2 = sA + 2048 + w * 512;
    short* lB1 = sB + w * 512;
    short* lB2 = sB + 2048 + w * 512;         // only when BN==128

    const int wm = (w >> 1) * 64, wn = (w & 1) * (BN / 2);
    const short* pa = sA + (wm + l15) * 32 + quad * 8;
    const short* pb = sB + (wn + l15) * 32 + quad * 8;

    f32x4 acc[4][NT] = {};
    for (int k0 = 0; k0 < K; k0 += 64) {
        #pragma unroll
        for (int s = 0; s < 2; s++) {
            const int ks = k0 + s * 32;
            GLDS16(gA + ks, lA1 + s * SUBA);
            GLDS16(gA + half64 + ks, lA2 + s * SUBA);
            GLDS16(gB + ks, lB1 + s * SUBB);
            if constexpr (BN == 128) GLDS16(gB + half64 + ks, lB2 + s * SUBB);
        }
        __syncthreads();
        #pragma unroll
        for (int s = 0; s < 2; s++) {
            bf16x8 af[4], bf[NT];
            #pragma unroll
            for (int mt = 0; mt < 4; mt++) af[mt] = *(const bf16x8*)(pa + s * SUBA + mt * 512);
            #pragma unroll
            for (int nt = 0; nt < NT; nt++) bf[nt] = *(const bf16x8*)(pb + s * SUBB + nt * 512);
            #pragma unroll
            for (int mt = 0; mt < 4; mt++)
                #pragma unroll
                for (int nt = 0; nt < NT; nt++)
                    acc[mt][nt] = __builtin_amdgcn_mfma_f32_16x16x32_bf16(af[mt], bf[nt], acc[mt][nt], 0, 0, 0);
        }
        __syncthreads();
    }
    #pragma unroll
    for (int mt = 0; mt < 4; mt++)
        #pragma unroll
        for (int nt = 0; nt < NT; nt++)
            #pragma unroll
            for (int r = 0; r < 4; r++) {
                int row = bm0 + wm + mt * 16 + quad * 4 + r;
                int col = bn0 + wn + nt * 16 + l15;
                if (F32OUT)
                    ((float*)Cv)[(size_t)row * N + col] = acc[mt][nt][r];
                else
                    ((short*)Cv)[(size_t)row * N + col] = f2bf(acc[mt][nt][r]);
            }
}

// ---------------------------------------------------------------------------
// Flash attention, causal, S^T formulation. q-tile 128 rows, 8 waves (512 thr).
// grid = 512 blocks; qt = b ? 15-t0 : t0 so co-resident pairs (ids +256) do
// constant work. KV tile = 64 keys/iter. Waves 0-3 stage K (4x GLDS,
// XOR-swizzled), waves 4-7 stage V (transposed, pitch 72). Per-wave compute:
// 16 q-rows; waves skip tiles fully above their causal diagonal.
// Scores in RAW units; exp via exp2 with c2 = scale*log2e folded into a fma.
// (Measured R13/R15/R16: 94-97us, MfmaUtil ~14.5, VALU ~34, conflicts 6.49e6
//  — barrier/latency-bound; VALU trims neutral; FROZEN.)
#define VP2 72
__global__ __launch_bounds__(512) void attn_kernel(const short* __restrict__ P,
                                                   short* __restrict__ O) {
    constexpr int S = 2048, ROWW = 6144, HD = 2048;
    const int id = blockIdx.x;
    const int b = id >> 8;
    const int rr = id & 255;
    const int h = rr & 15;
    const int t0 = rr >> 4;                    // 0..15
    const int qt = b ? (15 - t0) : t0;         // work balance across pairs
    const int wave = threadIdx.x >> 6, lane = threadIdx.x & 63;
    const int l15 = lane & 15, quad = lane >> 4;
    const int qRow = qt * 128 + wave * 16;
    const short* Pb = P + (size_t)b * S * ROWW;
    const short* Qp = Pb + h * 384;
    const short* Kp = Qp + 128;
    const short* Vp = Qp + 256;

    __shared__ short sK[2][64 * 128];   // swizzled chunk layout, 16 KB each
    __shared__ short sVt[2][128 * VP2]; // [d][key], 18 KB each

    // Q fragments (B operand, n=q=l15, k=d=quad*8+j)
    bf16x8 qf[4];
    #pragma unroll
    for (int f = 0; f < 4; f++)
        qf[f] = *(const bf16x8*)(Qp + (size_t)(qRow + l15) * ROWW + f * 32 + quad * 8);

    const bool isK = wave < 4;
    const int c1 = (wave & 3) * 64 + lane;
    const int krow1 = c1 >> 4;                 // 0..15
    const int kcol = ((c1 & 15) ^ (krow1 & 15)) * 8;
    const short* gK1 = Kp + (size_t)krow1 * ROWW + kcol;
    const short* gK2 = Kp + (size_t)(krow1 + 16) * ROWW + kcol;
    const short* gK3 = Kp + (size_t)(krow1 + 32) * ROWW + kcol;
    const short* gK4 = Kp + (size_t)(krow1 + 48) * ROWW + kcol;
    const int ldsOff1 = (wave & 3) * 512;
    const int ldsOff2 = 2048 + ldsOff1;
    const int ldsOff3 = 4096 + ldsOff1;
    const int ldsOff4 = 6144 + ldsOff1;
    const int vt = (int)threadIdx.x - 256;
    const int vKey = vt & 31;
    const int vD0 = (vt >> 5) * 8;
    const short* gV = Vp + (size_t)vKey * ROWW + vD0;
    const short* gV2 = Vp + (size_t)(vKey + 32) * ROWW + vD0;

    const int kTiles = qt * 2 + 2;             // 64-key tiles
    const float c2 = 0.12752741594977435f;     // (1/sqrt(128))*log2(e)
    const float THRR = 90.50966799f;           // 8*sqrt(128): defer-max, raw
    const int qG = qRow + l15;

    f32x4 accO[8] = {};                        // O^T: row=d(quad*4+r), col=q(l15)
    float m_i = NEG_BIG, l_i = 0.f;

    if (isK) {
        GLDS16(gK1, &sK[0][ldsOff1]);
        GLDS16(gK2, &sK[0][ldsOff2]);
        GLDS16(gK3, &sK[0][ldsOff3]);
        GLDS16(gK4, &sK[0][ldsOff4]);
    } else {
        bf16x8 v0 = *(const bf16x8*)(gV);
        bf16x8 v1 = *(const bf16x8*)(gV + 64);
        bf16x8 v2 = *(const bf16x8*)(gV2);
        bf16x8 v3 = *(const bf16x8*)(gV2 + 64);
        #pragma unroll
        for (int j = 0; j < 8; j++) {
            sVt[0][(vD0 + j) * VP2 + vKey] = v0[j];
            sVt[0][(vD0 + 64 + j) * VP2 + vKey] = v1[j];
            sVt[0][(vD0 + j) * VP2 + vKey + 32] = v2[j];
            sVt[0][(vD0 + 64 + j) * VP2 + vKey + 32] = v3[j];
        }
    }
    __syncthreads();

    for (int kt = 0; kt < kTiles; kt++) {
        const int cur = kt & 1, nxt = cur ^ 1;
        const bool pre = (kt + 1 < kTiles);
        bf16x8 v0n, v1n, v2n, v3n;
        if (pre) {
            const size_t kOff = (size_t)(kt + 1) * 64 * ROWW;
            if (isK) {
                GLDS16(gK1 + kOff, &sK[nxt][ldsOff1]);
                GLDS16(gK2 + kOff, &sK[nxt][ldsOff2]);
                GLDS16(gK3 + kOff, &sK[nxt][ldsOff3]);
                GLDS16(gK4 + kOff, &sK[nxt][ldsOff4]);
            } else {
                v0n = *(const bf16x8*)(gV + kOff);
                v1n = *(const bf16x8*)(gV + kOff + 64);
                v2n = *(const bf16x8*)(gV2 + kOff);
                v3n = *(const bf16x8*)(gV2 + kOff + 64);
            }
        }
        if (kt * 64 <= qRow + 15) {  // wave-uniform causal diagonal skip
            // QK^T transposed: sc[hh] row=key(hh*16+quad*4+r), col=q(l15); RAW
            f32x4 sc[4] = {};
            #pragma unroll
            for (int f = 0; f < 4; f++) {       // f-outer: 4 indep MFMA chains
                const int jj = ((4 * f + quad) ^ l15) * 8;
                #pragma unroll
                for (int hh = 0; hh < 4; hh++) {
                    bf16x8 kf = *(const bf16x8*)(&sK[cur][(hh * 16 + l15) * 128 + jj]);
                    sc[hh] = __builtin_amdgcn_mfma_f32_16x16x32_bf16(kf, qf[f], sc[hh], 0, 0, 0);
                }
            }
            if (kt * 64 + 63 > qRow) {          // diagonal tiles only: mask
                #pragma unroll
                for (int hh = 0; hh < 4; hh++)
                    #pragma unroll
                    for (int r = 0; r < 4; r++) {
                        const int key = kt * 64 + hh * 16 + quad * 4 + r;
                        if (key > qG) sc[hh][r] = NEG_BIG;
                    }
            }
            float mloc = sc[0][0];
            #pragma unroll
            for (int hh = 0; hh < 4; hh++)
                #pragma unroll
                for (int r = 0; r < 4; r++) mloc = fmaxf(mloc, sc[hh][r]);
            mloc = fmaxf(mloc, __shfl_xor(mloc, 16));
            mloc = fmaxf(mloc, __shfl_xor(mloc, 32));
            if (!__all(mloc <= m_i + THRR)) {  // T13 defer-max (raw units)
                const float nm = fmaxf(m_i, mloc);
                const float alpha = __builtin_exp2f((m_i - nm) * c2);
                m_i = nm;
                l_i *= alpha;
                #pragma unroll
                for (int t = 0; t < 8; t++)
                    #pragma unroll
                    for (int r = 0; r < 4; r++) accO[t][r] *= alpha;
            }
            const float mc2 = m_i * c2;
            float ssum = 0.f;
            #pragma unroll
            for (int hh = 0; hh < 4; hh++)
                #pragma unroll
                for (int r = 0; r < 4; r++) {
                    float p = __builtin_exp2f(__builtin_fmaf(sc[hh][r], c2, -mc2));
                    sc[hh][r] = p;
                    ssum += p;
                }
            ssum += __shfl_xor(ssum, 16);
            ssum += __shfl_xor(ssum, 32);
            l_i += ssum;
            // P^T (C-layout) -> B-frag via 8 shfl per 32-key slot; PV per slot
            #pragma unroll
            for (int s = 0; s < 2; s++) {
                const int d00 = pack2bf(sc[2 * s][0], sc[2 * s][1]);
                const int d01 = pack2bf(sc[2 * s][2], sc[2 * s][3]);
                const int d10 = pack2bf(sc[2 * s + 1][0], sc[2 * s + 1][1]);
                const int d11 = pack2bf(sc[2 * s + 1][2], sc[2 * s + 1][3]);
                const int srcA = l15 + ((quad & 1) << 5);
                const int srcB = srcA + 16;
                const int s00 = __shfl(d00, srcA), s01 = __shfl(d01, srcA);
                const int s02 = __shfl(d00, srcB), s03 = __shfl(d01, srcB);
                const int s10 = __shfl(d10, srcA), s11 = __shfl(d11, srcA);
                const int s12 = __shfl(d10, srcB), s13 = __shfl(d11, srcB);
                union { int i[4]; bf16x8 v; } pu;
                const bool lo = quad < 2;
                pu.i[0] = lo ? s00 : s10;
                pu.i[1] = lo ? s01 : s11;
                pu.i[2] = lo ? s02 : s12;
                pu.i[3] = lo ? s03 : s13;
                const bf16x8 pf = pu.v;
                // PV: O^T += V^T * P^T (keys s*32..s*32+31)
                #pragma unroll
                for (int t = 0; t < 8; t++) {
                    bf16x8 vf = *(const bf16x8*)(&sVt[cur][(t * 16 + l15) * VP2 + s * 32 + quad * 8]);
                    accO[t] = __builtin_amdgcn_mfma_f32_16x16x32_bf16(vf, pf, accO[t], 0, 0, 0);
                }
            }
        }
        if (pre && !isK) {
            #pragma unroll
            for (int j = 0; j < 8; j++) {
                sVt[nxt][(vD0 + j) * VP2 + vKey] = v0n[j];
                sVt[nxt][(vD0 + 64 + j) * VP2 + vKey] = v1n[j];
                sVt[nxt][(vD0 + j) * VP2 + vKey + 32] = v2n[j];
                sVt[nxt][(vD0 + 64 + j) * VP2 + vKey + 32] = v3n[j];
            }
        }
        __syncthreads();
    }
    const float inv = 1.0f / l_i;
    #pragma unroll
    for (int t = 0; t < 8; t++) {
        short4 st;
        st.x = f2bf(accO[t][0] * inv);
        st.y = f2bf(accO[t][1] * inv);
        st.z = f2bf(accO[t][2] * inv);
        st.w = f2bf(accO[t][3] * inv);
        *(short4*)(&O[(size_t)(b * S + qG) * HD + h * 128 + t * 16 + quad * 4]) = st;
    }
}

extern "C" void kernel_launch(void* const* d_in, const int* in_sizes, int n_in,
                              void* d_out, int out_size, void* d_ws, size_t ws_size,
                              hipStream_t stream) {
    const float* x     = (const float*)d_in[0];  // [2,2048,2048] fp32
    const float* w_in  = (const float*)d_in[1];  // [6144,2048]  fp32
    const float* w_out = (const float*)d_in[2];  // [2048,2048]  fp32
    float* out = (float*)d_out;                  // [2,2048,2048] fp32

    // Workspace (96 MiB): P[4096*6144] bf16 | xO[8388608] bf16 (x_bf16 then O)
    //                     | w_in_b[6144*2048] bf16 | w_out_b[2048*2048] bf16
    short* Pbuf   = (short*)d_ws;
    short* xObuf  = Pbuf  + (size_t)4096 * 6144;
    short* winb   = xObuf + (size_t)8388608;
    short* woutb  = winb  + (size_t)6144 * 2048;

    dim3 blk(256, 1, 1);
    const int nx = 2 * 2048 * 2048, nwi = 6144 * 2048, nwo = 2048 * 2048;
    // Fused bf16 conversion of all three inputs (one launch instead of three)
    const int c1 = nx / 4, c2 = c1 + nwi / 4;
    const int totalBlocks = (nx + nwi + nwo) / 1024;
    hipLaunchKernelGGL(cvt3_f32_bf16, dim3(totalBlocks), blk, 0, stream,
                       x, xObuf, w_in, winb, w_out, woutb, c1, c2);
    // GEMM1: P = x @ w_in^T (M=4096, N=6144, K=2048), bf16 out, BN=128 BK=64,
    // single 1536-block dispatch, default dispatch order (no swizzle).
    hipLaunchKernelGGL((gemm_bt<128, false>), dim3(48, 32, 1), blk, 0, stream,
                       xObuf, winb, (void*)Pbuf, 6144, 2048);
    // Flash attention (x_bf16 dead now; O overwrites it), 512 blocks x 512 thr
    hipLaunchKernelGGL(attn_kernel, dim3(512, 1, 1), dim3(512, 1, 1), 0, stream, Pbuf, xObuf);
    // GEMM2: out = O @ w_out^T (M=4096, N=2048, K=2048), fp32 out, BN=128 BK=64
    hipLaunchKernelGGL((gemm_bt<128, true>), dim3(16, 32, 1), blk, 0, stream, xObuf, woutb, (void*)out, 2048, 2048);
}